// Round 16
// baseline (428.675 us; speedup 1.0000x reference)
//
#include <hip/hip_runtime.h>
#include <hip/hip_fp16.h>
#include <hip/hip_cooperative_groups.h>
#include <math.h>

namespace cg = cooperative_groups;

// ---- problem constants (match reference) ----
#define NNODES 8704          // B*K = 512*17
#define NEDGE  139264
#define EPLUS  (NEDGE + NNODES)   // 147968 (self-loops appended)
#define NEG_SLOPE 0.2f
#define DEGCAP 64            // fixed CSR slot capacity; deg = Poisson(16)+1, P(>64) ~ 2e-14
#define LDSK   40            // gemm LDS row stride (32 + 8 fp16) -> 2-way banks
#define GRID   512           // cooperative grid: 2 blocks/CU guaranteed co-resident
#define BLK    256
#define SMEM_BYTES 34816     // As 10240 + Bs 20480 + p2s 4096

typedef _Float16 f16x8 __attribute__((ext_vector_type(8)));
typedef _Float16 f16x4 __attribute__((ext_vector_type(4)));
typedef float    f32x4 __attribute__((ext_vector_type(4)));

__device__ __forceinline__ float lrelu(float v) { return v >= 0.f ? v : NEG_SLOPE * v; }

// ================= phase bodies (shared by mega-kernel and fallback wrappers) =================

// ---- phase 0: zero cnt/alphasB, p-vectors, Wcat^T ----
__device__ __forceinline__ void phase_prep(int b, int t,
        const float* W1, const float* as1, const float* ad1,
        const float* W2, const float* as2, const float* ad2,
        float* pbuf, int* cnt, float* alphasB,
        _Float16* Wc1, _Float16* Wc2, char* smem) {
    if (b < 16) {
        for (int i = b * 256 + t; i < NNODES; i += 16 * 256) cnt[i] = 0;
        for (int i = b * 256 + t; i < NNODES * 8; i += 16 * 256) alphasB[i] = 0.f;
    }
    for (int u = b; u < 528; u += GRID) {
        __syncthreads();
        if (u < 16) {
            // p[u][k] = sum_c W[k][h*256+c]*a[h][c];  u = layer*8 + sd*4 + h
            float* a_sh = (float*)smem;
            const int layer = u >> 3, sd = (u >> 2) & 1, h = u & 3;
            const float* W  = layer ? W2 : W1;
            const float* av = layer ? (sd ? ad2 : as2) : (sd ? ad1 : as1);
            a_sh[t] = av[h * 256 + t];
            __syncthreads();
            float acc = 0.f;
            const float* Wr = W + (size_t)t * 1024 + h * 256;
#pragma unroll 8
            for (int c = 0; c < 256; ++c) acc += Wr[c] * a_sh[c];
            pbuf[u * 256 + t] = acc;
        } else {
            // Wcatt[o][h*256+k] = W[k][h*256+o] (fp16)
            float (*tile)[33] = (float(*)[33])smem;
            const int idx = u - 16;
            const int k0 = (idx & 7) * 32, o0 = ((idx >> 3) & 7) * 32;
            const int z = idx >> 6, layer = z >> 2, h = z & 3;
            const float* W = layer ? W2 : W1;
            _Float16* Wc   = layer ? Wc2 : Wc1;
#pragma unroll
            for (int p = 0; p < 4; ++p) {
                int e = t + p * 256; int kk = e >> 5, oo = e & 31;
                tile[kk][oo] = W[(size_t)(k0 + kk) * 1024 + h * 256 + o0 + oo];
            }
            __syncthreads();
#pragma unroll
            for (int p = 0; p < 4; ++p) {
                int e = t + p * 256; int oo = e >> 5, kk = e & 31;
                Wc[(size_t)(o0 + oo) * 1024 + h * 256 + k0 + kk] = (_Float16)tile[kk][oo];
            }
        }
    }
}

// ---- phase 1: CSR scatter + layer-1 alpha dots (+x0 -> fp16) ----
__device__ __forceinline__ void phase_scatter_alpha(int b, int t,
        const int* ei, int* cnt, int* csr,
        const float* x0, _Float16* x0h, const float* pbuf,
        float* asrc, float* adst) {
    for (int e = b * BLK + t; e < EPLUS; e += GRID * BLK) {
        int src, dst;
        if (e < NEDGE) { src = ei[e]; dst = ei[NEDGE + e]; }
        else           { src = dst = e - NEDGE; }
        int slot = atomicAdd(&cnt[dst], 1);
        if (slot < DEGCAP) csr[dst * DEGCAP + slot] = src;
    }
    const int w = t >> 6, l = t & 63;
    float4 pv[8];
#pragma unroll
    for (int v = 0; v < 8; ++v) pv[v] = *(const float4*)(pbuf + v * 256 + l * 4);
    for (int n = b * 4 + w; n < NNODES; n += GRID * 4) {
        float4 xv = *(const float4*)(x0 + (size_t)n * 256 + l * 4);
        f16x4 hv = {(_Float16)xv.x, (_Float16)xv.y, (_Float16)xv.z, (_Float16)xv.w};
        *(f16x4*)(x0h + (size_t)n * 256 + l * 4) = hv;
        float d[8];
#pragma unroll
        for (int v = 0; v < 8; ++v)
            d[v] = xv.x * pv[v].x + xv.y * pv[v].y + xv.z * pv[v].z + xv.w * pv[v].w;
#pragma unroll
        for (int off = 1; off <= 32; off <<= 1)
#pragma unroll
            for (int v = 0; v < 8; ++v) d[v] += __shfl_xor(d[v], off);
        if (l == 0) {
            *(float4*)(asrc + n * 4) = make_float4(d[0], d[1], d[2], d[3]);
            *(float4*)(adst + n * 4) = make_float4(d[4], d[5], d[6], d[7]);
        }
    }
}

// ---- agg: softmax + x-gather, wave = node, batch-8 load prefetch ----
__device__ __forceinline__ void phase_agg(int b, int t,
        const _Float16* xh, const int* cnt, const int* csr,
        const float* asrc, const float* adst, _Float16* y) {
    const int w = t >> 6, l = t & 63;
    const _Float16* xbase = xh + l * 4;
    for (int n = b * 4 + w; n < NNODES; n += GRID * 4) {
        int deg = cnt[n]; if (deg > DEGCAP) deg = DEGCAP;
        float4 ad = *(const float4*)(adst + n * 4);
        int src_l = 0;
        float w0 = 0.f, w1 = 0.f, w2 = 0.f, w3 = 0.f;
        if (l < deg) {
            src_l = csr[n * DEGCAP + l];
            float4 as = *(const float4*)(asrc + src_l * 4);
            w0 = __expf(lrelu(as.x + ad.x));
            w1 = __expf(lrelu(as.y + ad.y));
            w2 = __expf(lrelu(as.z + ad.z));
            w3 = __expf(lrelu(as.w + ad.w));
        }
        float d0 = w0, d1 = w1, d2 = w2, d3 = w3;
#pragma unroll
        for (int off = 32; off >= 1; off >>= 1) {
            d0 += __shfl_xor(d0, off);
            d1 += __shfl_xor(d1, off);
            d2 += __shfl_xor(d2, off);
            d3 += __shfl_xor(d3, off);
        }
        w0 /= d0; w1 /= d1; w2 /= d2; w3 /= d3;

        float acc[4][4] = {};   // [ch_sub][head]
        f16x4 xb[8], xn[8];
#pragma unroll
        for (int j = 0; j < 8; ++j) {
            int src = __shfl(src_l, j);
            if (j < deg) xb[j] = *(const f16x4*)(xbase + (size_t)src * 256);
        }
        for (int base = 0; base < deg; base += 8) {
#pragma unroll
            for (int j = 0; j < 8; ++j) {
                int s = base + 8 + j;
                int src = __shfl(src_l, s & 63);
                if (s < deg) xn[j] = *(const f16x4*)(xbase + (size_t)src * 256);
            }
#pragma unroll
            for (int j = 0; j < 8; ++j) {
                int s = base + j;
                if (s < deg) {
                    float u0 = __shfl(w0, s), u1 = __shfl(w1, s);
                    float u2 = __shfl(w2, s), u3 = __shfl(w3, s);
                    f16x4 xv = xb[j];
#pragma unroll
                    for (int c = 0; c < 4; ++c) {
                        float v = (float)xv[c];
                        acc[c][0] += u0 * v; acc[c][1] += u1 * v;
                        acc[c][2] += u2 * v; acc[c][3] += u3 * v;
                    }
                }
            }
#pragma unroll
            for (int j = 0; j < 8; ++j) xb[j] = xn[j];
        }
#pragma unroll
        for (int h = 0; h < 4; ++h) {
            f16x4 pv = {(_Float16)acc[0][h], (_Float16)acc[1][h],
                        (_Float16)acc[2][h], (_Float16)acc[3][h]};
            *(f16x4*)(y + (size_t)n * 1024 + h * 256 + l * 4) = pv;
        }
    }
}

// ---- gemm tile (R13 v5: BM=64, BN=128, BK=32, depth-2 register pipeline) ----
__device__ __forceinline__ void gemm_tile(const _Float16* __restrict__ Y,
        const _Float16* __restrict__ Wcatt, const float* __restrict__ bias,
        const float* __restrict__ p2, _Float16* __restrict__ outH,
        float* __restrict__ outF, float* __restrict__ asrc2, float* __restrict__ adst2,
        int bm, int bn, int t, char* smem) {
    _Float16* As = (_Float16*)smem;              // [2][64*LDSK]  10240 B
    _Float16* Bs = (_Float16*)(smem + 10240);    // [2][128*LDSK] 20480 B
    float* p2s   = (float*)(smem + 30720);       // 1024 f32      4096 B
    const int lane = t & 63;
    const int wave = t >> 6;
    const int wwr = wave >> 1, wwc = wave & 1;
    const int l15 = lane & 15, kb = lane >> 4;

    const int ar = t >> 2, ag = t & 3;
    const int br0 = t >> 2, br1 = 64 + (t >> 2), bg = t & 3;
    const _Float16* Yb  = Y     + (size_t)(bm + ar) * 1024 + ag * 8;
    const _Float16* Wb0 = Wcatt + (size_t)(bn + br0) * 1024 + bg * 8;
    const _Float16* Wb1 = Wcatt + (size_t)(bn + br1) * 1024 + bg * 8;
    const int aw = ar * LDSK + ag * 8;
    const int bw0 = br0 * LDSK + bg * 8, bw1 = br1 * LDSK + bg * 8;

    if (p2) {
#pragma unroll
        for (int p = 0; p < 4; ++p) {
            int e = t + p * 256;
            p2s[e] = p2[(e >> 7) * 256 + bn + (e & 127)];
        }
    }

    // prologue: tile 0 -> buffer 0; preload set0 = tile1, set1 = tile2
    {
        f16x8 a0 = *(const f16x8*)(Yb);
        f16x8 b0 = *(const f16x8*)(Wb0);
        f16x8 b1 = *(const f16x8*)(Wb1);
        *(f16x8*)(&As[aw])  = a0;
        *(f16x8*)(&Bs[bw0]) = b0;
        *(f16x8*)(&Bs[bw1]) = b1;
    }
    f16x8 a_s0 = *(const f16x8*)(Yb + 32);
    f16x8 bb_s0[2] = { *(const f16x8*)(Wb0 + 32), *(const f16x8*)(Wb1 + 32) };
    f16x8 a_s1 = *(const f16x8*)(Yb + 64);
    f16x8 bb_s1[2] = { *(const f16x8*)(Wb0 + 64), *(const f16x8*)(Wb1 + 64) };
    __syncthreads();

    f32x4 acc[2][4] = {};
    int a_off[2], b_off[4];
#pragma unroll
    for (int i = 0; i < 2; ++i) a_off[i] = (wwr * 32 + i * 16 + l15) * LDSK + kb * 8;
#pragma unroll
    for (int j = 0; j < 4; ++j) b_off[j] = (wwc * 64 + j * 16 + l15) * LDSK + kb * 8;

    for (int h = 0; h < 32; h += 2) {
        // half A: compute tile h (buf0), write set0 -> buf1, issue tile h+3 -> set0
        {
            f16x8 af[2], bf[4];
#pragma unroll
            for (int i = 0; i < 2; ++i) af[i] = *(const f16x8*)(&As[a_off[i]]);
#pragma unroll
            for (int j = 0; j < 4; ++j) bf[j] = *(const f16x8*)(&Bs[b_off[j]]);
#pragma unroll
            for (int i = 0; i < 2; ++i)
#pragma unroll
                for (int j = 0; j < 4; ++j)
                    acc[i][j] = __builtin_amdgcn_mfma_f32_16x16x32_f16(af[i], bf[j], acc[i][j], 0, 0, 0);
            *(f16x8*)(&As[2560 + aw])  = a_s0;
            *(f16x8*)(&Bs[5120 + bw0]) = bb_s0[0];
            *(f16x8*)(&Bs[5120 + bw1]) = bb_s0[1];
            if (h + 3 < 32) {
                int k = (h + 3) * 32;
                a_s0 = *(const f16x8*)(Yb + k);
                bb_s0[0] = *(const f16x8*)(Wb0 + k);
                bb_s0[1] = *(const f16x8*)(Wb1 + k);
            }
            __syncthreads();
        }
        // half B: compute tile h+1 (buf1), write set1 -> buf0, issue tile h+4 -> set1
        {
            f16x8 af[2], bf[4];
#pragma unroll
            for (int i = 0; i < 2; ++i) af[i] = *(const f16x8*)(&As[2560 + a_off[i]]);
#pragma unroll
            for (int j = 0; j < 4; ++j) bf[j] = *(const f16x8*)(&Bs[5120 + b_off[j]]);
#pragma unroll
            for (int i = 0; i < 2; ++i)
#pragma unroll
                for (int j = 0; j < 4; ++j)
                    acc[i][j] = __builtin_amdgcn_mfma_f32_16x16x32_f16(af[i], bf[j], acc[i][j], 0, 0, 0);
            if (h + 2 < 32) {
                *(f16x8*)(&As[aw])  = a_s1;
                *(f16x8*)(&Bs[bw0]) = bb_s1[0];
                *(f16x8*)(&Bs[bw1]) = bb_s1[1];
            }
            if (h + 4 < 32) {
                int k = (h + 4) * 32;
                a_s1 = *(const f16x8*)(Yb + k);
                bb_s1[0] = *(const f16x8*)(Wb0 + k);
                bb_s1[1] = *(const f16x8*)(Wb1 + k);
            }
            __syncthreads();
        }
    }

    // epilogue: C/D layout col=lane&15, row=(lane>>4)*4+q [m89-verified]
#pragma unroll
    for (int i = 0; i < 2; ++i)
#pragma unroll
        for (int q = 0; q < 4; ++q) {
            int row = bm + wwr * 32 + i * 16 + kb * 4 + q;
            float rv[4];
#pragma unroll
            for (int j = 0; j < 4; ++j) {
                int cl = wwc * 64 + j * 16 + l15;
                float r = 0.25f * acc[i][j][q] + bias[bn + cl];
                rv[j] = r;
                if (outH) outH[(size_t)row * 256 + bn + cl] = (_Float16)fmaxf(r, 0.f);
                else      outF[(size_t)row * 256 + bn + cl] = r;
            }
            if (p2) {
#pragma unroll
                for (int v = 0; v < 8; ++v) {
                    float ps = 0.f;
#pragma unroll
                    for (int j = 0; j < 4; ++j) {
                        int cl = wwc * 64 + j * 16 + l15;
                        ps += fmaxf(rv[j], 0.f) * p2s[v * 128 + cl];
                    }
#pragma unroll
                    for (int off = 1; off <= 8; off <<= 1) ps += __shfl_xor(ps, off);
                    if (l15 == 0) {
                        if (v < 4) atomicAdd(&asrc2[row * 4 + v], ps);
                        else       atomicAdd(&adst2[row * 4 + (v - 4)], ps);
                    }
                }
            }
        }
}

// ================= cooperative mega-kernel: all 6 phases, grid.sync between =================
__global__ __launch_bounds__(BLK, 2) void mega(const float* x0, const int* ei,
        const float* W1, const float* as1, const float* ad1, const float* b1,
        const float* W2, const float* as2, const float* ad2, const float* b2,
        float* out, _Float16* y, _Float16* x0h, _Float16* x1h,
        _Float16* Wc1, _Float16* Wc2, float* pbuf,
        float* asrcA, float* adstA, float* asrcB, float* adstB,
        int* cnt, int* csr) {
    cg::grid_group grid = cg::this_grid();
    __shared__ __align__(16) char smem[SMEM_BYTES];
    const int b = blockIdx.x, t = threadIdx.x;

    phase_prep(b, t, W1, as1, ad1, W2, as2, ad2, pbuf, cnt, asrcB, Wc1, Wc2, smem);
    grid.sync();
    phase_scatter_alpha(b, t, ei, cnt, csr, x0, x0h, pbuf, asrcA, adstA);
    grid.sync();
    phase_agg(b, t, x0h, cnt, csr, asrcA, adstA, y);
    grid.sync();
    if (b < 272) gemm_tile(y, Wc1, b1, pbuf + 2048, x1h, nullptr, asrcB, adstB,
                           (b >> 1) * 64, (b & 1) * 128, t, smem);
    grid.sync();
    phase_agg(b, t, x1h, cnt, csr, asrcB, adstB, y);
    grid.sync();
    if (b < 272) gemm_tile(y, Wc2, b2, nullptr, nullptr, out, nullptr, nullptr,
                           (b >> 1) * 64, (b & 1) * 128, t, smem);
}

// ================= fallback wrappers (same phase bodies, 6 plain launches) =================
__global__ __launch_bounds__(BLK) void k_prep(const float* W1, const float* as1, const float* ad1,
        const float* W2, const float* as2, const float* ad2,
        float* pbuf, int* cnt, float* alphasB, _Float16* Wc1, _Float16* Wc2) {
    __shared__ __align__(16) char smem[SMEM_BYTES];
    phase_prep(blockIdx.x, threadIdx.x, W1, as1, ad1, W2, as2, ad2, pbuf, cnt, alphasB, Wc1, Wc2, smem);
}
__global__ __launch_bounds__(BLK) void k_scatter_alpha(const int* ei, int* cnt, int* csr,
        const float* x0, _Float16* x0h, const float* pbuf, float* asrc, float* adst) {
    phase_scatter_alpha(blockIdx.x, threadIdx.x, ei, cnt, csr, x0, x0h, pbuf, asrc, adst);
}
__global__ __launch_bounds__(BLK) void k_agg(const _Float16* xh, const int* cnt, const int* csr,
        const float* asrc, const float* adst, _Float16* y) {
    phase_agg(blockIdx.x, threadIdx.x, xh, cnt, csr, asrc, adst, y);
}
__global__ __launch_bounds__(BLK) void k_gemm(const _Float16* Y, const _Float16* Wcatt,
        const float* bias, const float* p2, _Float16* outH, float* outF,
        float* asrc2, float* adst2) {
    __shared__ __align__(16) char smem[SMEM_BYTES];
    if (blockIdx.x < 272)
        gemm_tile(Y, Wcatt, bias, p2, outH, outF, asrc2, adst2,
                  ((int)blockIdx.x >> 1) * 64, ((int)blockIdx.x & 1) * 128, threadIdx.x, smem);
}

extern "C" void kernel_launch(void* const* d_in, const int* in_sizes, int n_in,
                              void* d_out, int out_size, void* d_ws, size_t ws_size,
                              hipStream_t stream) {
    const float* x0  = (const float*)d_in[0];
    const int*   ei  = (const int*)d_in[1];
    const float* W1  = (const float*)d_in[2];
    const float* as1 = (const float*)d_in[3];
    const float* ad1 = (const float*)d_in[4];
    const float* b1  = (const float*)d_in[5];
    const float* W2  = (const float*)d_in[6];
    const float* as2 = (const float*)d_in[7];
    const float* ad2 = (const float*)d_in[8];
    const float* b2  = (const float*)d_in[9];
    float* out = (float*)d_out;

    char* w = (char*)d_ws;
    _Float16* y   = (_Float16*)w; w += (size_t)NNODES * 1024 * 2;    // 17.8 MB
    _Float16* x0h = (_Float16*)w; w += (size_t)NNODES * 256 * 2;     // 4.5 MB
    _Float16* x1h = (_Float16*)w; w += (size_t)NNODES * 256 * 2;     // 4.5 MB
    _Float16* Wc1 = (_Float16*)w; w += (size_t)256 * 1024 * 2;       // 512 KB
    _Float16* Wc2 = (_Float16*)w; w += (size_t)256 * 1024 * 2;       // 512 KB
    float* pbuf   = (float*)w;    w += 16 * 256 * 4;                 // 16 KB
    float* asrcA  = (float*)w;    w += NNODES * 4 * 4;
    float* adstA  = (float*)w;    w += NNODES * 4 * 4;
    float* alphasB = (float*)w;   w += NNODES * 8 * 4;               // asrcB+adstB contiguous
    float* asrcB  = alphasB;
    float* adstB  = alphasB + NNODES * 4;
    int* cnt      = (int*)w;      w += NNODES * 4;
    int* csr      = (int*)w;      w += (size_t)NNODES * DEGCAP * 4;  // 2.2 MB

    void* args[] = { (void*)&x0, (void*)&ei, (void*)&W1, (void*)&as1, (void*)&ad1, (void*)&b1,
                     (void*)&W2, (void*)&as2, (void*)&ad2, (void*)&b2,
                     (void*)&out, (void*)&y, (void*)&x0h, (void*)&x1h,
                     (void*)&Wc1, (void*)&Wc2, (void*)&pbuf,
                     (void*)&asrcA, (void*)&adstA, (void*)&asrcB, (void*)&adstB,
                     (void*)&cnt, (void*)&csr };
    hipError_t err = hipLaunchCooperativeKernel((const void*)mega, dim3(GRID), dim3(BLK),
                                                args, 0, stream);
    if (err != hipSuccess) {
        // fallback: identical phases as 6 plain launches
        (void)hipGetLastError();
        k_prep<<<GRID, BLK, 0, stream>>>(W1, as1, ad1, W2, as2, ad2, pbuf, cnt, alphasB, Wc1, Wc2);
        k_scatter_alpha<<<GRID, BLK, 0, stream>>>(ei, cnt, csr, x0, x0h, pbuf, asrcA, adstA);
        k_agg<<<GRID, BLK, 0, stream>>>(x0h, cnt, csr, asrcA, adstA, y);
        k_gemm<<<272, BLK, 0, stream>>>(y, Wc1, b1, pbuf + 2048, x1h, nullptr, asrcB, adstB);
        k_agg<<<GRID, BLK, 0, stream>>>(x1h, cnt, csr, asrcB, adstB, y);
        k_gemm<<<272, BLK, 0, stream>>>(y, Wc2, b2, nullptr, nullptr, out, nullptr, nullptr);
    }
}

// Round 17
// 122.458 us; speedup vs baseline: 3.5006x; 3.5006x over previous
//
#include <hip/hip_runtime.h>
#include <hip/hip_fp16.h>
#include <math.h>

// ---- problem constants (match reference) ----
#define NNODES 8704          // B*K = 512*17
#define NEDGE  139264
#define EPLUS  (NEDGE + NNODES)   // 147968 (self-loops appended)
#define NEG_SLOPE 0.2f
#define DEGCAP 64            // fixed CSR slot capacity; deg = Poisson(16)+1, P(>64) ~ 2e-14
#define LDSK   40            // gemm LDS row stride (32 + 8 fp16) -> 2-way banks

#define NB_SC  ((EPLUS + 255) / 256)   // scatter blocks (579)
#define NB_AL  (NNODES / 4)            // alpha blocks (2176)
#define NB_WC  512                     // wcat blocks (8x8x8 flattened)

typedef _Float16 f16x8 __attribute__((ext_vector_type(8)));
typedef _Float16 f16x4 __attribute__((ext_vector_type(4)));
typedef float    f32x4 __attribute__((ext_vector_type(4)));

__device__ __forceinline__ float lrelu(float v) { return v >= 0.f ? v : NEG_SLOPE * v; }

// ---------------- K1 (16 blocks, tiny): p-vectors + zero cnt/alphasB ----------------
__global__ __launch_bounds__(256) void prep_pvec(const float* __restrict__ W1,
                                                 const float* __restrict__ as1,
                                                 const float* __restrict__ ad1,
                                                 const float* __restrict__ W2,
                                                 const float* __restrict__ as2,
                                                 const float* __restrict__ ad2,
                                                 float* __restrict__ pbuf,
                                                 int* __restrict__ cnt,
                                                 float* __restrict__ alphasB) {
    __shared__ float a_sh[256];
    const int b = blockIdx.x;
    const int t = threadIdx.x;
    for (int i = b * 256 + t; i < NNODES; i += 16 * 256) cnt[i] = 0;
    for (int i = b * 256 + t; i < NNODES * 8; i += 16 * 256) alphasB[i] = 0.f;
    const int layer = b >> 3, sd = (b >> 2) & 1, h = b & 3;
    const float* W  = layer ? W2 : W1;
    const float* av = layer ? (sd ? ad2 : as2) : (sd ? ad1 : as1);
    a_sh[t] = av[h * 256 + t];
    __syncthreads();
    float acc = 0.f;
    const float* Wr = W + (size_t)t * 1024 + h * 256;
#pragma unroll 8
    for (int c = 0; c < 256; ++c) acc += Wr[c] * a_sh[c];
    pbuf[b * 256 + t] = acc;
}

// ---------------- K2: edge scatter | layer-1 alpha dots | Wcat^T transpose ----------------
// wcat blocks depend only on W1/W2 (not on K1) -> moved here off the critical path
__global__ __launch_bounds__(256) void scatter_alpha_wcat(const int* __restrict__ ei,
                                                          int* __restrict__ cnt,
                                                          int* __restrict__ csr,
                                                          const float* __restrict__ xf,
                                                          _Float16* __restrict__ xh_out,
                                                          const float* __restrict__ p,
                                                          float* __restrict__ asrc,
                                                          float* __restrict__ adst,
                                                          const float* __restrict__ W1,
                                                          const float* __restrict__ W2,
                                                          _Float16* __restrict__ Wc1,
                                                          _Float16* __restrict__ Wc2) {
    __shared__ float tile[32][33];
    const int b = blockIdx.x;
    const int t = threadIdx.x;
    if (b < NB_SC) {
        int e = b * 256 + t;
        if (e >= EPLUS) return;
        int src, dst;
        if (e < NEDGE) { src = ei[e]; dst = ei[NEDGE + e]; }
        else           { src = dst = e - NEDGE; }
        int slot = atomicAdd(&cnt[dst], 1);
        if (slot < DEGCAP) csr[dst * DEGCAP + slot] = src;
    } else if (b < NB_SC + NB_AL) {
        const int wave = t >> 6, l = t & 63;
        const int n = (b - NB_SC) * 4 + wave;
        float4 pv[8];
#pragma unroll
        for (int v = 0; v < 8; ++v) pv[v] = *(const float4*)(p + v * 256 + l * 4);
        float4 xv = *(const float4*)(xf + (size_t)n * 256 + l * 4);
        f16x4 hv = {(_Float16)xv.x, (_Float16)xv.y, (_Float16)xv.z, (_Float16)xv.w};
        *(f16x4*)(xh_out + (size_t)n * 256 + l * 4) = hv;
        float d[8];
#pragma unroll
        for (int v = 0; v < 8; ++v)
            d[v] = xv.x * pv[v].x + xv.y * pv[v].y + xv.z * pv[v].z + xv.w * pv[v].w;
#pragma unroll
        for (int off = 1; off <= 32; off <<= 1)
#pragma unroll
            for (int v = 0; v < 8; ++v) d[v] += __shfl_xor(d[v], off);
        if (l == 0) {
            *(float4*)(asrc + n * 4) = make_float4(d[0], d[1], d[2], d[3]);
            *(float4*)(adst + n * 4) = make_float4(d[4], d[5], d[6], d[7]);
        }
    } else {
        // Wcatt[o][h*256+k] = W[k][h*256+o] (fp16)
        const int idx = b - NB_SC - NB_AL;         // 0..511
        const int k0 = (idx & 7) * 32, o0 = ((idx >> 3) & 7) * 32;
        const int z = idx >> 6;                    // 0..7
        const int layer = z >> 2, h = z & 3;
        const float* W = layer ? W2 : W1;
        _Float16* Wc   = layer ? Wc2 : Wc1;
#pragma unroll
        for (int pq = 0; pq < 4; ++pq) {
            int e = t + pq * 256; int kk = e >> 5, oo = e & 31;
            tile[kk][oo] = W[(size_t)(k0 + kk) * 1024 + h * 256 + o0 + oo];
        }
        __syncthreads();
#pragma unroll
        for (int pq = 0; pq < 4; ++pq) {
            int e = t + pq * 256; int oo = e >> 5, kk = e & 31;
            Wc[(size_t)(o0 + oo) * 1024 + h * 256 + k0 + kk] = (_Float16)tile[kk][oo];
        }
    }
}

// ---------------- softmax + x-gather v3: wave = node, batch-8 load prefetch ----------------
__global__ __launch_bounds__(256) void agg_gather(const _Float16* __restrict__ xh,
                                                  const int* __restrict__ cnt,
                                                  const int* __restrict__ csr,
                                                  const float* __restrict__ asrc,
                                                  const float* __restrict__ adst,
                                                  _Float16* __restrict__ y) {
    const int w = threadIdx.x >> 6, l = threadIdx.x & 63;
    const int n = blockIdx.x * 4 + w;
    int deg = cnt[n]; if (deg > DEGCAP) deg = DEGCAP;

    float4 ad = *(const float4*)(adst + n * 4);
    int src_l = 0;
    float w0 = 0.f, w1 = 0.f, w2 = 0.f, w3 = 0.f;
    if (l < deg) {
        src_l = csr[n * DEGCAP + l];
        float4 as = *(const float4*)(asrc + src_l * 4);
        w0 = __expf(lrelu(as.x + ad.x));
        w1 = __expf(lrelu(as.y + ad.y));
        w2 = __expf(lrelu(as.z + ad.z));
        w3 = __expf(lrelu(as.w + ad.w));
    }
    float d0 = w0, d1 = w1, d2 = w2, d3 = w3;
#pragma unroll
    for (int off = 32; off >= 1; off >>= 1) {
        d0 += __shfl_xor(d0, off);
        d1 += __shfl_xor(d1, off);
        d2 += __shfl_xor(d2, off);
        d3 += __shfl_xor(d3, off);
    }
    w0 /= d0; w1 /= d1; w2 /= d2; w3 /= d3;   // normalized weight of slot l

    const _Float16* xbase = xh + l * 4;
    float acc[4][4] = {};   // [ch_sub][head]
    f16x4 xb[8], xn[8];
#pragma unroll
    for (int j = 0; j < 8; ++j) {
        int src = __shfl(src_l, j);
        if (j < deg) xb[j] = *(const f16x4*)(xbase + (size_t)src * 256);
    }
    for (int base = 0; base < deg; base += 8) {
#pragma unroll
        for (int j = 0; j < 8; ++j) {
            int s = base + 8 + j;
            int src = __shfl(src_l, s & 63);
            if (s < deg) xn[j] = *(const f16x4*)(xbase + (size_t)src * 256);
        }
#pragma unroll
        for (int j = 0; j < 8; ++j) {
            int s = base + j;
            if (s < deg) {
                float u0 = __shfl(w0, s), u1 = __shfl(w1, s);
                float u2 = __shfl(w2, s), u3 = __shfl(w3, s);
                f16x4 xv = xb[j];
#pragma unroll
                for (int c = 0; c < 4; ++c) {
                    float v = (float)xv[c];
                    acc[c][0] += u0 * v; acc[c][1] += u1 * v;
                    acc[c][2] += u2 * v; acc[c][3] += u3 * v;
                }
            }
        }
#pragma unroll
        for (int j = 0; j < 8; ++j) xb[j] = xn[j];
    }
#pragma unroll
    for (int h = 0; h < 4; ++h) {
        f16x4 pv = {(_Float16)acc[0][h], (_Float16)acc[1][h],
                    (_Float16)acc[2][h], (_Float16)acc[3][h]};
        *(f16x4*)(y + (size_t)n * 1024 + h * 256 + l * 4) = pv;
    }
}

// ---------------- output GEMM v6 (depth-2 pipeline, BM=32): out = 0.25*Y@Wcatt^T + bias ----------------
// BM=32, BN=128, BK=32; grid (272, 2) = 544 blocks -> ~2.1 blocks/CU, 2 waves/SIMD.
// 256 thr / 4 waves (2x2), wave tile 16x64 = 1x4 frags, 4 MFMA/step.
// Depth-2 register pipeline: batches issued 3 tiles ahead; one barrier per K-step.
__global__ __launch_bounds__(256) void gemm_out(const _Float16* __restrict__ Y,
                                                const _Float16* __restrict__ Wcatt,
                                                const float* __restrict__ bias,
                                                const float* __restrict__ p2,
                                                _Float16* __restrict__ outH,  // relu+fp16 if non-null
                                                float* __restrict__ outF,
                                                float* __restrict__ asrc2,
                                                float* __restrict__ adst2) {
    __shared__ __align__(16) _Float16 As[2][32 * LDSK];    // 5.1 KB
    __shared__ __align__(16) _Float16 Bs[2][128 * LDSK];   // 20.5 KB
    __shared__ float p2s[8 * 128];                         // 4 KB
    const int t    = threadIdx.x;
    const int lane = t & 63;
    const int wave = t >> 6;
    const int wwr = wave >> 1, wwc = wave & 1;
    const int bm = blockIdx.x * 32;
    const int bn = blockIdx.y * 128;
    const int l15 = lane & 15, kb = lane >> 4;

    // staging coords: A 1 chunk/thread for t<128 (32 rows x 4 chunks), B 2 chunks/thread
    const int ar = t >> 2, ag = t & 3;            // valid for t<128
    const int br0 = t >> 2, br1 = 64 + (t >> 2), bg = t & 3;
    const _Float16* Yb  = Y     + (size_t)(bm + (ar & 31)) * 1024 + ag * 8;
    const _Float16* Wb0 = Wcatt + (size_t)(bn + br0) * 1024 + bg * 8;
    const _Float16* Wb1 = Wcatt + (size_t)(bn + br1) * 1024 + bg * 8;
    const int aw = (ar & 31) * LDSK + ag * 8;
    const int bw0 = br0 * LDSK + bg * 8, bw1 = br1 * LDSK + bg * 8;
    const bool do_a = (t < 128);

    if (p2) {
#pragma unroll
        for (int p = 0; p < 4; ++p) {
            int e = t + p * 256;              // [v][c], c in 0..127
            p2s[e] = p2[(e >> 7) * 256 + bn + (e & 127)];
        }
    }

    // prologue: tile 0 -> buffer 0; preload set0 = batch1, set1 = batch2
    {
        f16x8 b0 = *(const f16x8*)(Wb0);
        f16x8 b1 = *(const f16x8*)(Wb1);
        if (do_a) {
            f16x8 a0 = *(const f16x8*)(Yb);
            *(f16x8*)(&As[0][aw]) = a0;
        }
        *(f16x8*)(&Bs[0][bw0]) = b0;
        *(f16x8*)(&Bs[0][bw1]) = b1;
    }
    f16x8 a_s0 = {}, a_s1 = {};
    if (do_a) { a_s0 = *(const f16x8*)(Yb + 32); a_s1 = *(const f16x8*)(Yb + 64); }
    f16x8 bb_s0[2] = { *(const f16x8*)(Wb0 + 32), *(const f16x8*)(Wb1 + 32) };
    f16x8 bb_s1[2] = { *(const f16x8*)(Wb0 + 64), *(const f16x8*)(Wb1 + 64) };
    __syncthreads();

    f32x4 acc[4] = {};
    int a_off, b_off[4];
    a_off = (wwr * 16 + l15) * LDSK + kb * 8;
#pragma unroll
    for (int j = 0; j < 4; ++j) b_off[j] = (wwc * 64 + j * 16 + l15) * LDSK + kb * 8;

    for (int h = 0; h < 32; h += 2) {
        // ---- half A: compute tile h (buf 0), write batch h+1 (set0) -> buf 1, issue h+3 -> set0
        {
            f16x8 af = *(const f16x8*)(&As[0][a_off]);
            f16x8 bf[4];
#pragma unroll
            for (int j = 0; j < 4; ++j) bf[j] = *(const f16x8*)(&Bs[0][b_off[j]]);
#pragma unroll
            for (int j = 0; j < 4; ++j)
                acc[j] = __builtin_amdgcn_mfma_f32_16x16x32_f16(af, bf[j], acc[j], 0, 0, 0);
            if (do_a) *(f16x8*)(&As[1][aw]) = a_s0;
            *(f16x8*)(&Bs[1][bw0]) = bb_s0[0];
            *(f16x8*)(&Bs[1][bw1]) = bb_s0[1];
            if (h + 3 < 32) {
                int k = (h + 3) * 32;
                if (do_a) a_s0 = *(const f16x8*)(Yb + k);
                bb_s0[0] = *(const f16x8*)(Wb0 + k);
                bb_s0[1] = *(const f16x8*)(Wb1 + k);
            }
            __syncthreads();
        }
        // ---- half B: compute tile h+1 (buf 1), write batch h+2 (set1) -> buf 0, issue h+4 -> set1
        {
            f16x8 af = *(const f16x8*)(&As[1][a_off]);
            f16x8 bf[4];
#pragma unroll
            for (int j = 0; j < 4; ++j) bf[j] = *(const f16x8*)(&Bs[1][b_off[j]]);
#pragma unroll
            for (int j = 0; j < 4; ++j)
                acc[j] = __builtin_amdgcn_mfma_f32_16x16x32_f16(af, bf[j], acc[j], 0, 0, 0);
            if (h + 2 < 32) {
                if (do_a) *(f16x8*)(&As[0][aw]) = a_s1;
                *(f16x8*)(&Bs[0][bw0]) = bb_s1[0];
                *(f16x8*)(&Bs[0][bw1]) = bb_s1[1];
            }
            if (h + 4 < 32) {
                int k = (h + 4) * 32;
                if (do_a) a_s1 = *(const f16x8*)(Yb + k);
                bb_s1[0] = *(const f16x8*)(Wb0 + k);
                bb_s1[1] = *(const f16x8*)(Wb1 + k);
            }
            __syncthreads();
        }
    }

    // epilogue: C/D layout col=lane&15, row=(lane>>4)*4+q [m89-verified]
#pragma unroll
    for (int q = 0; q < 4; ++q) {
        int row = bm + wwr * 16 + kb * 4 + q;
        float rv[4];
#pragma unroll
        for (int j = 0; j < 4; ++j) {
            int cl = wwc * 64 + j * 16 + l15;     // 0..127 within block
            float r = 0.25f * acc[j][q] + bias[bn + cl];
            rv[j] = r;
            if (outH) outH[(size_t)row * 256 + bn + cl] = (_Float16)fmaxf(r, 0.f);
            else      outF[(size_t)row * 256 + bn + cl] = r;
        }
        if (p2) {
            // layer-2 alpha partial dots on relu(x1) (f32-exact), this block's 128 cols
#pragma unroll
            for (int v = 0; v < 8; ++v) {
                float ps = 0.f;
#pragma unroll
                for (int j = 0; j < 4; ++j) {
                    int cl = wwc * 64 + j * 16 + l15;
                    ps += fmaxf(rv[j], 0.f) * p2s[v * 128 + cl];
                }
#pragma unroll
                for (int off = 1; off <= 8; off <<= 1) ps += __shfl_xor(ps, off);
                if (l15 == 0) {
                    if (v < 4) atomicAdd(&asrc2[row * 4 + v], ps);
                    else       atomicAdd(&adst2[row * 4 + (v - 4)], ps);
                }
            }
        }
    }
}

extern "C" void kernel_launch(void* const* d_in, const int* in_sizes, int n_in,
                              void* d_out, int out_size, void* d_ws, size_t ws_size,
                              hipStream_t stream) {
    const float* x0  = (const float*)d_in[0];
    const int*   ei  = (const int*)d_in[1];
    const float* W1  = (const float*)d_in[2];
    const float* as1 = (const float*)d_in[3];
    const float* ad1 = (const float*)d_in[4];
    const float* b1  = (const float*)d_in[5];
    const float* W2  = (const float*)d_in[6];
    const float* as2 = (const float*)d_in[7];
    const float* ad2 = (const float*)d_in[8];
    const float* b2  = (const float*)d_in[9];
    float* out = (float*)d_out;

    char* w = (char*)d_ws;
    _Float16* y   = (_Float16*)w; w += (size_t)NNODES * 1024 * 2;    // 17.8 MB
    _Float16* x0h = (_Float16*)w; w += (size_t)NNODES * 256 * 2;     // 4.5 MB
    _Float16* x1h = (_Float16*)w; w += (size_t)NNODES * 256 * 2;     // 4.5 MB
    _Float16* Wc1 = (_Float16*)w; w += (size_t)256 * 1024 * 2;       // 512 KB
    _Float16* Wc2 = (_Float16*)w; w += (size_t)256 * 1024 * 2;       // 512 KB
    float* pbuf   = (float*)w;    w += 16 * 256 * 4;                 // 16 KB
    float* asrcA  = (float*)w;    w += NNODES * 4 * 4;
    float* adstA  = (float*)w;    w += NNODES * 4 * 4;
    float* alphasB = (float*)w;   w += NNODES * 8 * 4;               // asrcB+adstB
    float* asrcB  = alphasB;
    float* adstB  = alphasB + NNODES * 4;
    int* cnt      = (int*)w;      w += NNODES * 4;
    int* csr      = (int*)w;      w += (size_t)NNODES * DEGCAP * 4;  // 2.2 MB

    const dim3 gemm_grid(NNODES / 32, 2);

    // K1 (tiny, 16 blocks): p-vectors + zero scratch
    prep_pvec<<<16, 256, 0, stream>>>(W1, as1, ad1, W2, as2, ad2, pbuf, cnt, alphasB);
    // K2: CSR scatter | layer-1 alpha dots + x0->fp16 | Wcat transposes (off critical path)
    scatter_alpha_wcat<<<NB_SC + NB_AL + NB_WC, 256, 0, stream>>>(
        ei, cnt, csr, x0, x0h, pbuf, asrcA, adstA, W1, W2, Wc1, Wc2);

    // ---- layer 1 ----
    agg_gather<<<NNODES / 4, 256, 0, stream>>>(x0h, cnt, csr, asrcA, adstA, y);
    gemm_out<<<gemm_grid, 256, 0, stream>>>(y, Wc1, b1, pbuf + 8 * 256, x1h, nullptr, asrcB, adstB);

    // ---- layer 2 ----
    agg_gather<<<NNODES / 4, 256, 0, stream>>>(x1h, cnt, csr, asrcB, adstB, y);
    gemm_out<<<gemm_grid, 256, 0, stream>>>(y, Wc2, b2, nullptr, nullptr, out, nullptr, nullptr);
}